// Round 11
// baseline (253.747 us; speedup 1.0000x reference)
//
#include <hip/hip_runtime.h>

#define N_NODES 50000
#define N_EDGES 1600000
#define F 32
#define BSH 7                               // 128 nodes per bucket
#define BSIZE (1 << BSH)
#define NB ((N_NODES + BSIZE - 1) >> BSH)   // 391 buckets
#define FILL_CHUNK 6144                     // 261 blocks; runs ~15.7 entries
#define EMASK 0x1FFFFF
#define BHIST_BLOCKS 512
#define PNB 16                              // nodes per h_project block
#define EO_BLOCKS 4096

typedef float f4 __attribute__((ext_vector_type(4)));
typedef float f8 __attribute__((ext_vector_type(8)));
typedef _Float16 h4 __attribute__((ext_vector_type(4)));
typedef _Float16 h8 __attribute__((ext_vector_type(8)));

__device__ __forceinline__ f4 nt_load4(const float* p) {
    return __builtin_nontemporal_load((const f4*)p);
}
__device__ __forceinline__ int nt_loadi(const int* p) {
    return __builtin_nontemporal_load(p);
}
__device__ __forceinline__ unsigned short nt_loadu16(const unsigned short* p) {
    return __builtin_nontemporal_load(p);
}

// ---------- fused: bucket histogram + (last block) scan ----------
__global__ __launch_bounds__(256)
void k_bhist_scan(const int* __restrict__ dst,
                  int* __restrict__ bhist,
                  int* __restrict__ done_ctr,
                  int* __restrict__ bucket_off,
                  int* __restrict__ cursor) {
    __shared__ int lh[NB];
    __shared__ int s[256];
    __shared__ int cvals[2 * 256];
    __shared__ int isLast;

    for (int i = threadIdx.x; i < NB; i += 256) lh[i] = 0;
    __syncthreads();
    for (int e = blockIdx.x * blockDim.x + threadIdx.x; e < N_EDGES;
         e += gridDim.x * blockDim.x)
        atomicAdd(&lh[dst[e] >> BSH], 1);
    __syncthreads();
    for (int i = threadIdx.x; i < NB; i += 256)
        if (lh[i]) atomicAdd(&bhist[i], lh[i]);

    __threadfence();
    if (threadIdx.x == 0)
        isLast = (atomicAdd(done_ctr, 1) == (int)gridDim.x - 1);
    __syncthreads();
    if (!isLast) return;

    // last block: scan 391 counts (coherent atomic reads), 2 entries/thread
    int t = threadIdx.x;
    int c0 = (2 * t     < NB) ? atomicAdd(&bhist[2 * t], 0)     : 0;
    int c1 = (2 * t + 1 < NB) ? atomicAdd(&bhist[2 * t + 1], 0) : 0;
    cvals[2 * t] = c0; cvals[2 * t + 1] = c1;
    int sum = c0 + c1;
    s[t] = sum;
    __syncthreads();
    for (int off = 1; off < 256; off <<= 1) {
        int u = (t >= off) ? s[t - off] : 0;
        __syncthreads();
        s[t] += u;
        __syncthreads();
    }
    int ex = s[t] - sum;   // exclusive over pairs
    if (2 * t < NB)     { bucket_off[2 * t] = ex;          cursor[2 * t] = ex; }
    if (2 * t + 1 < NB) { bucket_off[2 * t + 1] = ex + c0; cursor[2 * t + 1] = ex + c0; }
    if (t == 255) bucket_off[NB] = s[255];
}

// ---------- phase A: bin edges into bucket runs; one global read of dst/src ----------
__global__ __launch_bounds__(256)
void k_coarse_fill(const int* __restrict__ dst,
                   const int* __restrict__ src,
                   int* __restrict__ cursor,
                   int* __restrict__ coarseE,
                   unsigned short* __restrict__ coarseS) {
    __shared__ int lh[NB];
    __shared__ int gb[NB];
    __shared__ unsigned int ds[FILL_CHUNK];   // d<<16 | src, staged coalesced
    int lo = blockIdx.x * FILL_CHUNK;
    int hi = min(lo + FILL_CHUNK, N_EDGES);
    int n_e = hi - lo;

    for (int i = threadIdx.x; i < NB; i += 256) lh[i] = 0;
    __syncthreads();
    for (int i = threadIdx.x; i < n_e; i += 256) {
        int d = dst[lo + i];
        ds[i] = ((unsigned)d << 16) | (unsigned)src[lo + i];
        atomicAdd(&lh[d >> BSH], 1);
    }
    __syncthreads();
    for (int i = threadIdx.x; i < NB; i += 256) {
        gb[i] = atomicAdd(&cursor[i], lh[i]);
        lh[i] = 0;                  // reuse as rank counter
    }
    __syncthreads();
    for (int i = threadIdx.x; i < n_e; i += 256) {
        unsigned v = ds[i];
        int d = (int)(v >> 16);
        int bk = d >> BSH;
        int r = atomicAdd(&lh[bk], 1);
        int p = gb[bk] + r;
        coarseE[p] = (lo + i) | ((d & (BSIZE - 1)) << 21);   // e < 2^21
        coarseS[p] = (unsigned short)(v & 0xFFFFu);
    }
}

// ---------- phase B: exact CSR within each 128-node bucket ----------
__global__ __launch_bounds__(256)
void k_exact_fill(const int* __restrict__ coarseE,
                  const unsigned short* __restrict__ coarseS,
                  const int* __restrict__ bucket_off,
                  int* __restrict__ row_off,
                  int* __restrict__ eid_sorted,
                  unsigned short* __restrict__ src_sorted) {
    __shared__ int cnt[BSIZE];
    __shared__ int s[BSIZE];
    __shared__ int cur[BSIZE];
    int tid = threadIdx.x;
    int b = blockIdx.x;
    int lo = bucket_off[b], hi = bucket_off[b + 1];

    if (tid < BSIZE) cnt[tid] = 0;
    __syncthreads();
    for (int i = lo + tid; i < hi; i += 256)
        atomicAdd(&cnt[(nt_loadi(&coarseE[i]) >> 21) & (BSIZE - 1)], 1);
    __syncthreads();
    if (tid < BSIZE) s[tid] = cnt[tid];
    __syncthreads();
    for (int off = 1; off < BSIZE; off <<= 1) {
        int v = 0;
        if (tid < BSIZE && tid >= off) v = s[tid - off];
        __syncthreads();
        if (tid < BSIZE) s[tid] += v;
        __syncthreads();
    }
    int nbase = b << BSH;
    if (tid < BSIZE) {
        int base = lo + s[tid] - cnt[tid];   // exclusive scan + bucket base
        cur[tid] = base;
        if (nbase + tid < N_NODES) row_off[nbase + tid] = base;
    }
    if (b == NB - 1 && tid == 0) row_off[N_NODES] = N_EDGES;
    __syncthreads();
    for (int i = lo + tid; i < hi; i += 256) {
        int ev = nt_loadi(&coarseE[i]);
        int l = (ev >> 21) & (BSIZE - 1);
        int p = atomicAdd(&cur[l], 1);
        eid_sorted[p] = ev & EMASK;
        src_sorted[p] = nt_loadu16(&coarseS[i]);
    }
}

// ---------- stage 1+2: node_mean (f16 out) via per-node wave reduce ----------
__global__ __launch_bounds__(256)
void k_node_mean(const float* __restrict__ inputs,
                 const int* __restrict__ eid_sorted,
                 const int* __restrict__ row_off,
                 _Float16* __restrict__ node_mean) {
    int wave = (blockIdx.x * blockDim.x + threadIdx.x) >> 6;
    if (wave >= N_NODES) return;
    int lane  = threadIdx.x & 63;
    int eslot = lane >> 3;       // 0..7
    int q     = lane & 7;        // float4 quad

    int s0 = row_off[wave];
    int s1 = row_off[wave + 1];

    f4 acc = {0.f, 0.f, 0.f, 0.f};
    int i = s0 + eslot;
    int e = (i < s1) ? eid_sorted[i] : 0;
    while (i < s1) {
        int inext = i + 8;
        int enext = (inext < s1) ? eid_sorted[inext] : 0;   // prefetch next eid
        f4 v = nt_load4(&inputs[(size_t)e * F + q * 4]);    // NT: zero reuse
        acc += v;
        i = inext; e = enext;
    }
    #pragma unroll
    for (int m = 8; m <= 32; m <<= 1) {
        acc.x += __shfl_xor(acc.x, m);
        acc.y += __shfl_xor(acc.y, m);
        acc.z += __shfl_xor(acc.z, m);
        acc.w += __shfl_xor(acc.w, m);
    }
    if (eslot == 0) {
        float r = 1.0f / fmaxf((float)(s1 - s0), 1.0f);
        f4 o = acc * r;
        *reinterpret_cast<h4*>(&node_mean[(size_t)wave * F + q * 4]) =
            __builtin_convertvector(o, h4);
    }
}

// ---------- stage 3 + projection fused: node_p(f16) = (sum mean[src]) @ W^T ----------
// 16 nodes/block (4/wave): W staged once per 16 nodes; 16B h8 gathers (4 lanes/edge).
__global__ __launch_bounds__(256)
void k_node_h_project(const unsigned short* __restrict__ src_sorted,
                      const int* __restrict__ row_off,
                      const _Float16* __restrict__ node_mean,
                      const float* __restrict__ W,
                      _Float16* __restrict__ node_p) {
    __shared__ float Wl[32][33];
    __shared__ float hr[PNB][36];

    int tid = threadIdx.x;
    #pragma unroll
    for (int i = tid; i < 1024; i += 256) Wl[i >> 5][i & 31] = W[i];

    int wv  = tid >> 6;          // wave 0..3
    int lane = tid & 63;
    int es  = lane >> 2;         // edge slot 0..15
    int q2  = lane & 3;          // h8 slot -> features q2*8..q2*8+7
    int nb0 = blockIdx.x * PNB;  // N_NODES = 3125*16, no tail

    #pragma unroll
    for (int k = 0; k < 4; ++k) {
        int n = nb0 + wv * 4 + k;
        int s0 = row_off[n], s1 = row_off[n + 1];
        f8 acc = {0.f, 0.f, 0.f, 0.f, 0.f, 0.f, 0.f, 0.f};
        int i = s0 + es;
        int sN = (i < s1) ? (int)src_sorted[i] : 0;
        while (i < s1) {
            int inext = i + 16;
            int snext = (inext < s1) ? (int)src_sorted[inext] : 0;
            h8 v = *reinterpret_cast<const h8*>(&node_mean[(size_t)sN * F + q2 * 8]);
            acc += __builtin_convertvector(v, f8);
            i = inext; sN = snext;
        }
        #pragma unroll
        for (int m = 4; m <= 32; m <<= 1) {
            #pragma unroll
            for (int j = 0; j < 8; ++j) acc[j] += __shfl_xor(acc[j], m);
        }
        if (es == 0) {
            f4 lo4 = __builtin_shufflevector(acc, acc, 0, 1, 2, 3);
            f4 hi4 = __builtin_shufflevector(acc, acc, 4, 5, 6, 7);
            *reinterpret_cast<f4*>(&hr[wv * 4 + k][q2 * 8])     = lo4;
            *reinterpret_cast<f4*>(&hr[wv * 4 + k][q2 * 8 + 4]) = hi4;
        }
    }
    __syncthreads();

    for (int idx = tid; idx < PNB * 32; idx += 256) {
        int n = idx >> 5;
        int o = idx & 31;
        float sacc = 0.f;
        #pragma unroll
        for (int i2 = 0; i2 < 32; ++i2) sacc += hr[n][i2] * Wl[o][i2];
        node_p[(size_t)(nb0 + n) * F + o] = (_Float16)sacc;
    }
}

// ---------- stage 4: out[e] = 0.5*(node_p[src] + node_p[dst]) + b ----------
// 4 threads/edge, 16B gathers, grid-stride; bias hoisted (q2 loop-invariant).
__global__ __launch_bounds__(256)
void k_edge_out(const int* __restrict__ src,
                const int* __restrict__ dst,
                const _Float16* __restrict__ node_p,
                const float* __restrict__ b,
                float* __restrict__ out) {
    int q2 = threadIdx.x & 3;
    f4 bb0 = *reinterpret_cast<const f4*>(&b[q2 * 8]);
    f4 bb1 = *reinterpret_cast<const f4*>(&b[q2 * 8 + 4]);
    int stride = gridDim.x * blockDim.x;          // multiple of 4 -> q2 invariant
    for (int t = blockIdx.x * blockDim.x + threadIdx.x; t < N_EDGES * 4; t += stride) {
        int e = t >> 2;
        int s = nt_loadi(&src[e]);
        int d = nt_loadi(&dst[e]);

        h8 ah = *reinterpret_cast<const h8*>(&node_p[(size_t)s * F + q2 * 8]);
        h8 ch = *reinterpret_cast<const h8*>(&node_p[(size_t)d * F + q2 * 8]);
        f8 a = __builtin_convertvector(ah, f8);
        f8 c = __builtin_convertvector(ch, f8);
        f8 r = 0.5f * (a + c);

        f4 r0 = __builtin_shufflevector(r, r, 0, 1, 2, 3) + bb0;
        f4 r1 = __builtin_shufflevector(r, r, 4, 5, 6, 7) + bb1;
        float* o = &out[(size_t)e * F + q2 * 8];
        __builtin_nontemporal_store(r0, (f4*)o);
        __builtin_nontemporal_store(r1, (f4*)(o + 4));
    }
}

extern "C" void kernel_launch(void* const* d_in, const int* in_sizes, int n_in,
                              void* d_out, int out_size, void* d_ws, size_t ws_size,
                              hipStream_t stream) {
    const float* inputs = (const float*)d_in[0];
    const int*   src    = (const int*)d_in[1];
    const int*   dst    = (const int*)d_in[2];
    const float* W      = (const float*)d_in[3];
    const float* b      = (const float*)d_in[4];
    float* out = (float*)d_out;

    // Workspace layout: f16 tables first (16B aligned), then ints, then u16.
    _Float16* node_mean = (_Float16*)d_ws;                 // N*F
    _Float16* node_p    = node_mean + (size_t)N_NODES * F; // N*F
    int*  coarseE    = (int*)(node_p + (size_t)N_NODES * F);  // E
    int*  eid_sorted = coarseE + N_EDGES;                  // E
    int*  bhist      = eid_sorted + N_EDGES;               // NB
    int*  done_ctr   = bhist + NB;                         // 1
    int*  bucket_off = done_ctr + 1;                       // NB+1
    int*  cursor     = bucket_off + NB + 1;                // NB
    int*  row_off    = cursor + NB;                        // N+1
    unsigned short* coarseS    = (unsigned short*)(row_off + N_NODES + 1); // E
    unsigned short* src_sorted = coarseS + N_EDGES;        // E

    hipMemsetAsync(bhist, 0, (NB + 1) * sizeof(int), stream);  // bhist + done_ctr

    k_bhist_scan<<<BHIST_BLOCKS, 256, 0, stream>>>(
        dst, bhist, done_ctr, bucket_off, cursor);
    k_coarse_fill<<<(N_EDGES + FILL_CHUNK - 1) / FILL_CHUNK, 256, 0, stream>>>(
        dst, src, cursor, coarseE, coarseS);
    k_exact_fill<<<NB, 256, 0, stream>>>(
        coarseE, coarseS, bucket_off, row_off, eid_sorted, src_sorted);

    int node_blocks = (N_NODES + 3) / 4;   // 1 wave per node, 4 waves/block
    k_node_mean<<<node_blocks, 256, 0, stream>>>(inputs, eid_sorted, row_off, node_mean);
    k_node_h_project<<<N_NODES / PNB, 256, 0, stream>>>(
        src_sorted, row_off, node_mean, W, node_p);
    k_edge_out<<<EO_BLOCKS, 256, 0, stream>>>(src, dst, node_p, b, out);
}

// Round 12
// 216.842 us; speedup vs baseline: 1.1702x; 1.1702x over previous
//
#include <hip/hip_runtime.h>

#define N_NODES 50000
#define N_EDGES 1600000
#define F 32
#define BSH 7                               // 128 nodes per bucket
#define BSIZE (1 << BSH)
#define NB ((N_NODES + BSIZE - 1) >> BSH)   // 391 buckets
#define FILL_CHUNK 6144                     // 261 blocks; runs ~15.7 entries
#define EMASK 0x1FFFFF

typedef float f4 __attribute__((ext_vector_type(4)));
typedef _Float16 h4 __attribute__((ext_vector_type(4)));

__device__ __forceinline__ f4 nt_load4(const float* p) {
    return __builtin_nontemporal_load((const f4*)p);
}
__device__ __forceinline__ int nt_loadi(const int* p) {
    return __builtin_nontemporal_load(p);
}
__device__ __forceinline__ unsigned short nt_loadu16(const unsigned short* p) {
    return __builtin_nontemporal_load(p);
}

// ---------- coarse bucket histogram (LDS-privatized) ----------
__global__ __launch_bounds__(256)
void k_bhist(const int* __restrict__ dst, int* __restrict__ bhist) {
    __shared__ int lh[NB];
    for (int i = threadIdx.x; i < NB; i += 256) lh[i] = 0;
    __syncthreads();
    for (int e = blockIdx.x * blockDim.x + threadIdx.x; e < N_EDGES;
         e += gridDim.x * blockDim.x)
        atomicAdd(&lh[dst[e] >> BSH], 1);
    __syncthreads();
    for (int i = threadIdx.x; i < NB; i += 256)
        if (lh[i]) atomicAdd(&bhist[i], lh[i]);
}

// ---------- scan 391 bucket counts -> offsets + fill cursors ----------
__global__ __launch_bounds__(512)
void k_bscan(const int* __restrict__ bhist,
             int* __restrict__ bucket_off,
             int* __restrict__ cursor) {
    __shared__ int s[512];
    int t = threadIdx.x;
    int v = (t < NB) ? bhist[t] : 0;
    s[t] = v;
    __syncthreads();
    for (int off = 1; off < 512; off <<= 1) {
        int u = (t >= off) ? s[t - off] : 0;
        __syncthreads();
        s[t] += u;
        __syncthreads();
    }
    if (t < NB) {
        int ex = s[t] - v;
        bucket_off[t] = ex;
        cursor[t] = ex;
    }
    if (t == NB - 1) bucket_off[NB] = s[t];
}

// ---------- phase A: bin edges into bucket runs; one global read of dst/src ----------
__global__ __launch_bounds__(256)
void k_coarse_fill(const int* __restrict__ dst,
                   const int* __restrict__ src,
                   int* __restrict__ cursor,
                   int* __restrict__ coarseE,
                   unsigned short* __restrict__ coarseS) {
    __shared__ int lh[NB];
    __shared__ int gb[NB];
    __shared__ unsigned int ds[FILL_CHUNK];   // d<<16 | src, staged coalesced
    int lo = blockIdx.x * FILL_CHUNK;
    int hi = min(lo + FILL_CHUNK, N_EDGES);
    int n_e = hi - lo;

    for (int i = threadIdx.x; i < NB; i += 256) lh[i] = 0;
    __syncthreads();
    for (int i = threadIdx.x; i < n_e; i += 256) {
        int d = dst[lo + i];
        ds[i] = ((unsigned)d << 16) | (unsigned)src[lo + i];
        atomicAdd(&lh[d >> BSH], 1);
    }
    __syncthreads();
    for (int i = threadIdx.x; i < NB; i += 256) {
        gb[i] = atomicAdd(&cursor[i], lh[i]);
        lh[i] = 0;                  // reuse as rank counter
    }
    __syncthreads();
    for (int i = threadIdx.x; i < n_e; i += 256) {
        unsigned v = ds[i];
        int d = (int)(v >> 16);
        int bk = d >> BSH;
        int r = atomicAdd(&lh[bk], 1);
        int p = gb[bk] + r;
        coarseE[p] = (lo + i) | ((d & (BSIZE - 1)) << 21);   // e < 2^21
        coarseS[p] = (unsigned short)(v & 0xFFFFu);
    }
}

// ---------- phase B: exact CSR within each 128-node bucket ----------
__global__ __launch_bounds__(256)
void k_exact_fill(const int* __restrict__ coarseE,
                  const unsigned short* __restrict__ coarseS,
                  const int* __restrict__ bucket_off,
                  int* __restrict__ row_off,
                  int* __restrict__ eid_sorted,
                  unsigned short* __restrict__ src_sorted) {
    __shared__ int cnt[BSIZE];
    __shared__ int s[BSIZE];
    __shared__ int cur[BSIZE];
    int tid = threadIdx.x;
    int b = blockIdx.x;
    int lo = bucket_off[b], hi = bucket_off[b + 1];

    if (tid < BSIZE) cnt[tid] = 0;
    __syncthreads();
    for (int i = lo + tid; i < hi; i += 256)
        atomicAdd(&cnt[(nt_loadi(&coarseE[i]) >> 21) & (BSIZE - 1)], 1);
    __syncthreads();
    if (tid < BSIZE) s[tid] = cnt[tid];
    __syncthreads();
    for (int off = 1; off < BSIZE; off <<= 1) {
        int v = 0;
        if (tid < BSIZE && tid >= off) v = s[tid - off];
        __syncthreads();
        if (tid < BSIZE) s[tid] += v;
        __syncthreads();
    }
    int nbase = b << BSH;
    if (tid < BSIZE) {
        int base = lo + s[tid] - cnt[tid];   // exclusive scan + bucket base
        cur[tid] = base;
        if (nbase + tid < N_NODES) row_off[nbase + tid] = base;
    }
    if (b == NB - 1 && tid == 0) row_off[N_NODES] = N_EDGES;
    __syncthreads();
    for (int i = lo + tid; i < hi; i += 256) {
        int ev = nt_loadi(&coarseE[i]);
        int l = (ev >> 21) & (BSIZE - 1);
        int p = atomicAdd(&cur[l], 1);
        eid_sorted[p] = ev & EMASK;
        src_sorted[p] = nt_loadu16(&coarseS[i]);
    }
}

// ---------- stage 1+2: node_mean (f16 out) via per-node wave reduce ----------
__global__ __launch_bounds__(256)
void k_node_mean(const float* __restrict__ inputs,
                 const int* __restrict__ eid_sorted,
                 const int* __restrict__ row_off,
                 _Float16* __restrict__ node_mean) {
    int wave = (blockIdx.x * blockDim.x + threadIdx.x) >> 6;
    if (wave >= N_NODES) return;
    int lane  = threadIdx.x & 63;
    int eslot = lane >> 3;       // 0..7
    int q     = lane & 7;        // float4 quad

    int s0 = row_off[wave];
    int s1 = row_off[wave + 1];

    f4 acc = {0.f, 0.f, 0.f, 0.f};
    int i = s0 + eslot;
    int e = (i < s1) ? eid_sorted[i] : 0;
    while (i < s1) {
        int inext = i + 8;
        int enext = (inext < s1) ? eid_sorted[inext] : 0;   // prefetch next eid
        f4 v = nt_load4(&inputs[(size_t)e * F + q * 4]);    // NT: zero reuse
        acc += v;
        i = inext; e = enext;
    }
    #pragma unroll
    for (int m = 8; m <= 32; m <<= 1) {
        acc.x += __shfl_xor(acc.x, m);
        acc.y += __shfl_xor(acc.y, m);
        acc.z += __shfl_xor(acc.z, m);
        acc.w += __shfl_xor(acc.w, m);
    }
    if (eslot == 0) {
        float r = 1.0f / fmaxf((float)(s1 - s0), 1.0f);
        f4 o = acc * r;
        *reinterpret_cast<h4*>(&node_mean[(size_t)wave * F + q * 4]) =
            __builtin_convertvector(o, h4);
    }
}

// ---------- stage 3 + projection fused: node_p(f16) = (sum mean[src]) @ W^T ----------
__global__ __launch_bounds__(256)
void k_node_h_project(const unsigned short* __restrict__ src_sorted,
                      const int* __restrict__ row_off,
                      const _Float16* __restrict__ node_mean,
                      const float* __restrict__ W,
                      _Float16* __restrict__ node_p) {
    __shared__ float Wl[32][33];
    __shared__ float hr[4][36];   // stride 36: float4-aligned rows

    int tid = threadIdx.x;
    #pragma unroll
    for (int i = tid; i < 1024; i += 256) Wl[i >> 5][i & 31] = W[i];

    int wv    = tid >> 6;        // wave 0..3 = local node
    int lane  = tid & 63;
    int eslot = lane >> 3;
    int q     = lane & 7;
    int n     = blockIdx.x * 4 + wv;     // N_NODES = 12500*4, no tail

    int s0 = row_off[n];
    int s1 = row_off[n + 1];

    f4 acc = {0.f, 0.f, 0.f, 0.f};
    int i = s0 + eslot;
    int s = (i < s1) ? (int)src_sorted[i] : 0;
    while (i < s1) {
        int inext = i + 8;
        int snext = (inext < s1) ? (int)src_sorted[inext] : 0;
        h4 v = *reinterpret_cast<const h4*>(&node_mean[(size_t)s * F + q * 4]);
        acc += __builtin_convertvector(v, f4);
        i = inext; s = snext;
    }
    #pragma unroll
    for (int m = 8; m <= 32; m <<= 1) {
        acc.x += __shfl_xor(acc.x, m);
        acc.y += __shfl_xor(acc.y, m);
        acc.z += __shfl_xor(acc.z, m);
        acc.w += __shfl_xor(acc.w, m);
    }
    if (eslot == 0) {
        *reinterpret_cast<f4*>(&hr[wv][q * 4]) = acc;
    }
    __syncthreads();

    if (tid < 128) {
        int ln = tid >> 5;       // local node
        int o  = tid & 31;       // output channel
        float sacc = 0.f;
        #pragma unroll
        for (int i2 = 0; i2 < 32; ++i2) sacc += hr[ln][i2] * Wl[o][i2];
        node_p[(size_t)(blockIdx.x * 4 + ln) * F + o] = (_Float16)sacc;
    }
}

// ---------- stage 4: out[e] = 0.5*(node_p[src] + node_p[dst]) + b ----------
__global__ __launch_bounds__(256)
void k_edge_out(const int* __restrict__ src,
                const int* __restrict__ dst,
                const _Float16* __restrict__ node_p,
                const float* __restrict__ b,
                float* __restrict__ out) {
    int tid = blockIdx.x * blockDim.x + threadIdx.x;   // e*8 + q
    if (tid >= N_EDGES * 8) return;
    int e = tid >> 3;
    int q = tid & 7;
    int s = nt_loadi(&src[e]);     // streamed once: keep out of L2
    int d = nt_loadi(&dst[e]);

    h4 ah = *reinterpret_cast<const h4*>(&node_p[(size_t)s * F + q * 4]);
    h4 ch = *reinterpret_cast<const h4*>(&node_p[(size_t)d * F + q * 4]);
    const f4 a  = __builtin_convertvector(ah, f4);
    const f4 c  = __builtin_convertvector(ch, f4);
    const f4 bb = *reinterpret_cast<const f4*>(&b[q * 4]);

    f4 r = 0.5f * (a + c) + bb;
    __builtin_nontemporal_store(r, (f4*)&out[(size_t)e * F + q * 4]);
}

extern "C" void kernel_launch(void* const* d_in, const int* in_sizes, int n_in,
                              void* d_out, int out_size, void* d_ws, size_t ws_size,
                              hipStream_t stream) {
    const float* inputs = (const float*)d_in[0];
    const int*   src    = (const int*)d_in[1];
    const int*   dst    = (const int*)d_in[2];
    const float* W      = (const float*)d_in[3];
    const float* b      = (const float*)d_in[4];
    float* out = (float*)d_out;

    // Workspace layout: 4B-aligned ints first, f16/ushort (2B) last.
    int*  coarseE    = (int*)d_ws;                         // E
    int*  eid_sorted = coarseE + N_EDGES;                  // E
    int*  bhist      = eid_sorted + N_EDGES;               // NB
    int*  bucket_off = bhist + NB;                         // NB+1
    int*  cursor     = bucket_off + NB + 1;                // NB
    int*  row_off    = cursor + NB;                        // N+1
    _Float16* node_mean = (_Float16*)(row_off + N_NODES + 1);       // N*F
    _Float16* node_p    = node_mean + (size_t)N_NODES * F;          // N*F
    unsigned short* coarseS    = (unsigned short*)(node_p + (size_t)N_NODES * F); // E
    unsigned short* src_sorted = coarseS + N_EDGES;        // E

    hipMemsetAsync(bhist, 0, NB * sizeof(int), stream);

    k_bhist<<<512, 256, 0, stream>>>(dst, bhist);
    k_bscan<<<1, 512, 0, stream>>>(bhist, bucket_off, cursor);
    k_coarse_fill<<<(N_EDGES + FILL_CHUNK - 1) / FILL_CHUNK, 256, 0, stream>>>(
        dst, src, cursor, coarseE, coarseS);
    k_exact_fill<<<NB, 256, 0, stream>>>(
        coarseE, coarseS, bucket_off, row_off, eid_sorted, src_sorted);

    int node_blocks = (N_NODES + 3) / 4;   // 1 wave per node, 4 waves/block
    k_node_mean<<<node_blocks, 256, 0, stream>>>(inputs, eid_sorted, row_off, node_mean);
    k_node_h_project<<<N_NODES / 4, 256, 0, stream>>>(
        src_sorted, row_off, node_mean, W, node_p);
    k_edge_out<<<(N_EDGES * 8 + 255) / 256, 256, 0, stream>>>(src, dst, node_p, b, out);
}